// Round 3
// baseline (239.013 us; speedup 1.0000x reference)
//
#include <hip/hip_runtime.h>

#define NB 16
#define KK 128
#define CC 64
#define NBLOCKS 1024

// 2*log2(e): A2/B2 pre-scaled so tanh(x) = 1 - 2/(exp2(s)+1), s = scaled (a+b)
#define TSCALE 2.8853900817779268f

__device__ __forceinline__ float tanh_pre(float s) {
    // s = 2*log2(e)*x ; tanh(x) = 1 - 2/(2^s + 1)
    return fmaf(-2.f, __builtin_amdgcn_rcpf(__builtin_amdgcn_exp2f(s) + 1.f), 1.f);
}

__global__ __launch_bounds__(256, 4) void fused_kernel(
    const float* __restrict__ t, const float* __restrict__ x,
    const float* __restrict__ E,
    const float* __restrict__ W_lin, const float* __restrict__ b_lin,
    const float* __restrict__ W_u1, const float* __restrict__ b_u1,
    const float* __restrict__ W_u2, const float* __restrict__ b_u2,
    const float* __restrict__ W_b1, const float* __restrict__ b_b1,
    const float* __restrict__ W_b2, const float* __restrict__ b_b2,
    float* __restrict__ A2, float* __restrict__ B2, float* __restrict__ unary,
    unsigned* __restrict__ bar, float* __restrict__ out)
{
    __shared__ float2 Gs[2][4][CC];   // [j][wave][c], .x/.y = edge type   4 KiB
    __shared__ float2 Ssh[2][4];      // per-(j,wave) sum_i E
    __shared__ float2 Gred[2][CC];    // reduced G                         1 KiB
    __shared__ float  Accs[2][4][CC]; // epilogue partials                 2 KiB

    const int tid  = threadIdx.x;
    const int lane = tid & 63;
    const int w    = tid >> 6;

    // ---------------- Phase 1: rows (waves 0,1 only) ----------------
    if (w < 2) {
        const int r = blockIdx.x * 2 + w;          // row in [0, N*K)

        const float xv = x[r * CC + lane];
        float h = fmaf(t[0], W_lin[lane], b_lin[lane]);
#pragma unroll 8
        for (int k = 0; k < CC; ++k) {
            float xk = __shfl(xv, k);
            h = fmaf(xk, W_lin[(k + 1) * CC + lane], h);
        }

        float u1 = b_u1[lane];
        float a0 = b_b1[lane], a1 = b_b1[CC + lane];
        float bb0 = 0.f, bb1 = 0.f;
#pragma unroll 4
        for (int k = 0; k < CC; ++k) {
            float hk = __shfl(h, k);
            u1  = fmaf(hk, W_u1[k * CC + lane], u1);
            a0  = fmaf(hk, W_b1[k * CC + lane], a0);
            bb0 = fmaf(hk, W_b1[(CC + k) * CC + lane], bb0);
            a1  = fmaf(hk, W_b1[2 * CC * CC + k * CC + lane], a1);
            bb1 = fmaf(hk, W_b1[2 * CC * CC + (CC + k) * CC + lane], bb1);
        }

        float tu = tanh_pre(TSCALE * u1);
        float u2 = b_u2[lane];
#pragma unroll 8
        for (int k = 0; k < CC; ++k) {
            float uk = __shfl(tu, k);
            u2 = fmaf(uk, W_u2[k * CC + lane], u2);
        }

        const int idx = r * CC + lane;
        unary[idx] = u2;
        ((float2*)A2)[idx] = make_float2(TSCALE * a0, TSCALE * a1);
        ((float2*)B2)[idx] = make_float2(TSCALE * bb0, TSCALE * bb1);
    }

    // ---------------- grid barrier (all 1024 blocks co-resident) ----------------
    __syncthreads();
    if (tid == 0) {
        __threadfence();
        __hip_atomic_fetch_add(bar, 1u, __ATOMIC_RELEASE, __HIP_MEMORY_SCOPE_AGENT);
        while (__hip_atomic_load(bar, __ATOMIC_ACQUIRE, __HIP_MEMORY_SCOPE_AGENT) < NBLOCKS) {
            __builtin_amdgcn_s_sleep(2);
        }
    }
    __syncthreads();
    __threadfence();

    // ---------------- Phase 2: one (n, j-pair) per block ----------------
    const int n  = blockIdx.x >> 6;
    const int j0 = (blockIdx.x & 63) * 2;

    const float2* A2v = (const float2*)A2;
    const float2* B2v = (const float2*)B2;
    const float2* Ev  = (const float2*)E;

    const float2 a20 = A2v[(n * KK + j0) * CC + lane];
    const float2 a21 = A2v[(n * KK + j0 + 1) * CC + lane];
    const float2* B2p = B2v + (n * KK + w * 32) * CC + lane;
    const float2* Ep  = Ev + (n * KK + w * 32) * KK;

    float2 g0 = make_float2(0.f, 0.f), g1 = make_float2(0.f, 0.f);
    float s00 = 0.f, s01 = 0.f, s10 = 0.f, s11 = 0.f;
#pragma unroll 8
    for (int i = 0; i < 32; ++i) {
        float2 bb = B2p[i * CC];
        float2 w0 = Ep[i * KK + j0];
        float2 w1 = Ep[i * KK + j0 + 1];
        float t00 = tanh_pre(a20.x + bb.x);
        float t01 = tanh_pre(a20.y + bb.y);
        float t10 = tanh_pre(a21.x + bb.x);
        float t11 = tanh_pre(a21.y + bb.y);
        g0.x = fmaf(w0.x, t00, g0.x);  g0.y = fmaf(w0.y, t01, g0.y);
        g1.x = fmaf(w1.x, t10, g1.x);  g1.y = fmaf(w1.y, t11, g1.y);
        s00 += w0.x;  s01 += w0.y;
        s10 += w1.x;  s11 += w1.y;
    }
    Gs[0][w][lane] = g0;
    Gs[1][w][lane] = g1;
    if (lane == 0) {
        Ssh[0][w] = make_float2(s00, s01);
        Ssh[1][w] = make_float2(s10, s11);
    }
    __syncthreads();

    // reduce wave partials: 128 (j,c) cells over 4 waves
    if (tid < 128) {
        int js = tid >> 6, c = tid & 63;
        float2 q0 = Gs[js][0][c], q1 = Gs[js][1][c], q2 = Gs[js][2][c], q3 = Gs[js][3][c];
        Gred[js][c] = make_float2(q0.x + q1.x + q2.x + q3.x, q0.y + q1.y + q2.y + q3.y);
    }
    __syncthreads();

    // epilogue matvec, h-range split across waves; lane = output channel c
    float acc0 = 0.f, acc1 = 0.f;
#pragma unroll
    for (int hi = 0; hi < 16; ++hi) {
        const int hh = w * 16 + hi;
        float2 q0 = Gred[0][hh];
        float2 q1 = Gred[1][hh];
        float wa = W_b2[hh * CC + lane];
        float wb = W_b2[CC * CC + hh * CC + lane];
        acc0 = fmaf(q0.x, wa, acc0);  acc0 = fmaf(q0.y, wb, acc0);
        acc1 = fmaf(q1.x, wa, acc1);  acc1 = fmaf(q1.y, wb, acc1);
    }
    Accs[0][w][lane] = acc0;
    Accs[1][w][lane] = acc1;
    __syncthreads();

    if (w < 2) {
        const int rj = n * KK + j0 + w;
        float a = Accs[w][0][lane] + Accs[w][1][lane] + Accs[w][2][lane] + Accs[w][3][lane];
        float2 sA = Ssh[w][0], sB = Ssh[w][1], sC = Ssh[w][2], sD = Ssh[w][3];
        float St0 = sA.x + sB.x + sC.x + sD.x;
        float St1 = sA.y + sB.y + sC.y + sD.y;
        a += b_b2[lane] * St0 + b_b2[CC + lane] * St1;
        out[rj * CC + lane] = unary[rj * CC + lane] + a * (1.f / 128.f);
    }
}

extern "C" void kernel_launch(void* const* d_in, const int* in_sizes, int n_in,
                              void* d_out, int out_size, void* d_ws, size_t ws_size,
                              hipStream_t stream) {
    const float* t     = (const float*)d_in[0];
    const float* x     = (const float*)d_in[1];
    const float* E     = (const float*)d_in[2];
    const float* W_lin = (const float*)d_in[3];
    const float* b_lin = (const float*)d_in[4];
    const float* W_u1  = (const float*)d_in[5];
    const float* b_u1  = (const float*)d_in[6];
    const float* W_u2  = (const float*)d_in[7];
    const float* b_u2  = (const float*)d_in[8];
    const float* W_b1  = (const float*)d_in[9];
    const float* b_b1  = (const float*)d_in[10];
    const float* W_b2  = (const float*)d_in[11];
    const float* b_b2  = (const float*)d_in[12];
    float* out = (float*)d_out;

    float* ws    = (float*)d_ws;
    float* A2    = ws;                        // 2*N*K*C floats (e-interleaved, prescaled)
    float* B2    = ws + 2 * NB * KK * CC;     // 2*N*K*C
    float* unary = ws + 4 * NB * KK * CC;     // N*K*C
    unsigned* bar = (unsigned*)(ws + 5 * NB * KK * CC);

    hipMemsetAsync(bar, 0, sizeof(unsigned), stream);
    fused_kernel<<<NBLOCKS, 256, 0, stream>>>(
        t, x, E, W_lin, b_lin, W_u1, b_u1, W_u2, b_u2, W_b1, b_b1, W_b2, b_b2,
        A2, B2, unary, bar, out);
}

// Round 4
// 28.450 us; speedup vs baseline: 8.4013x; 8.4013x over previous
//
#include <hip/hip_runtime.h>

#define NB 16
#define KK 128
#define CC 64

// 2*log2(e): A2/B2 pre-scaled so tanh(x) = 1 - 2/(exp2(s)+1), s = scaled (a+b)
#define TSCALE 2.8853900817779268f

__device__ __forceinline__ float tanh_pre(float s) {
    // s = 2*log2(e)*x ; tanh(x) = 1 - 2/(2^s + 1)
    return fmaf(-2.f, __builtin_amdgcn_rcpf(__builtin_amdgcn_exp2f(s) + 1.f), 1.f);
}

// Kernel 1: 256 blocks x 512 threads; wave = one row r = n*K+k.
//   h      = [t, x_r] @ W_lin + b_lin
//   unary  = tanh(h@W_u1+b_u1)@W_u2 + b_u2
//   A2[r]  = TSCALE*(h @ W_b1[e][0:C] + b_b1[e])   (receiver/j part, e interleaved)
//   B2[r]  = TSCALE*(h @ W_b1[e][C:2C])            (sender/i part,   e interleaved)
// W_b1 (64 KiB, > L1) staged in LDS once per block -> weight L2 traffic ~29 MB total.
__global__ __launch_bounds__(512) void precompute_kernel(
    const float* __restrict__ t, const float* __restrict__ x,
    const float* __restrict__ W_lin, const float* __restrict__ b_lin,
    const float* __restrict__ W_u1, const float* __restrict__ b_u1,
    const float* __restrict__ W_u2, const float* __restrict__ b_u2,
    const float* __restrict__ W_b1, const float* __restrict__ b_b1,
    float* __restrict__ A2, float* __restrict__ B2, float* __restrict__ unary)
{
    __shared__ float Wb1s[2 * 2 * CC * CC];   // 64 KiB, same layout as W_b1 [ET][2C][C]

    const int tid = threadIdx.x;
    {   // stage W_b1: 16384 floats = 4096 float4, 8 per thread
        const float4* src = (const float4*)W_b1;
        float4* dst = (float4*)Wb1s;
#pragma unroll
        for (int it = 0; it < 8; ++it) dst[tid + it * 512] = src[tid + it * 512];
    }
    __syncthreads();

    const int lane = tid & 63;
    const int r    = blockIdx.x * 8 + (tid >> 6);   // row in [0, N*K)

    const float xv = x[r * CC + lane];
    float h = fmaf(t[0], W_lin[lane], b_lin[lane]);
#pragma unroll 8
    for (int k = 0; k < CC; ++k) {
        float xk = __shfl(xv, k);
        h = fmaf(xk, W_lin[(k + 1) * CC + lane], h);
    }

    float u1 = b_u1[lane];
    float a0 = b_b1[lane], a1 = b_b1[CC + lane];
    float bb0 = 0.f, bb1 = 0.f;
#pragma unroll 4
    for (int k = 0; k < CC; ++k) {
        float hk = __shfl(h, k);
        u1  = fmaf(hk, W_u1[k * CC + lane], u1);
        a0  = fmaf(hk, Wb1s[k * CC + lane], a0);
        bb0 = fmaf(hk, Wb1s[(CC + k) * CC + lane], bb0);
        a1  = fmaf(hk, Wb1s[2 * CC * CC + k * CC + lane], a1);
        bb1 = fmaf(hk, Wb1s[2 * CC * CC + (CC + k) * CC + lane], bb1);
    }

    float tu = tanh_pre(TSCALE * u1);
    float u2 = b_u2[lane];
#pragma unroll 8
    for (int k = 0; k < CC; ++k) {
        float uk = __shfl(tu, k);
        u2 = fmaf(uk, W_u2[k * CC + lane], u2);
    }

    const int idx = r * CC + lane;
    unary[idx] = u2;
    ((float2*)A2)[idx] = make_float2(TSCALE * a0, TSCALE * a1);
    ((float2*)B2)[idx] = make_float2(TSCALE * bb0, TSCALE * bb1);
}

// Kernel 2: 256 blocks x 512 threads; block = (n, 8 consecutive j); wave owns one j.
//   G[e,h] = sum_i E[n,i,j,e] * tanh-from-prescaled(A[e,n,j,h] + B[e,n,i,h])
//   out[n,j,c] = unary + (1/K) * sum_e (G[e]@W_b2[e] + b_b2[e]*sum_i E)
// B2[n] (64 KiB) staged via async split: issue all loads, write+compute half 0
// while half 1 is in flight. S = sum_i E is wave-uniform (no reduce needed).
__global__ __launch_bounds__(512) void binary_kernel(
    const float* __restrict__ E, const float* __restrict__ W_b2,
    const float* __restrict__ b_b2, const float* __restrict__ A2,
    const float* __restrict__ B2, const float* __restrict__ unary,
    float* __restrict__ out)
{
    __shared__ float  Bs[KK * CC * 2];   // 64 KiB  [i][h][e]
    __shared__ float2 Es[8 * KK];        //  8 KiB  [w][i]  (.x/.y = edge type)
    __shared__ float2 Gsh[8 * CC];       //  4 KiB  [w][h]

    const int tid  = threadIdx.x;
    const int lane = tid & 63;
    const int w    = tid >> 6;
    const int n    = blockIdx.x >> 4;          // 16 j-groups per n
    const int j0   = (blockIdx.x & 15) * 8;
    const int rj   = n * KK + j0 + w;

    // prefetch own-j operands (independent of staging)
    const float2 a2 = ((const float2*)A2)[rj * CC + lane];
    const float  un = unary[rj * CC + lane];

    const float4* Bsrc = (const float4*)(B2 + n * KK * CC * 2);
    float4* Bdst = (float4*)Bs;
    const float2* E2 = (const float2*)E;

    // E column for this wave's j (lines shared across the 8 waves)
    float2 e0 = E2[(n * KK + lane) * KK + j0 + w];
    float2 e1 = E2[(n * KK + 64 + lane) * KK + j0 + w];

    // issue ALL B2 loads (half 0 and half 1) up front
    float4 b0a = Bsrc[tid],        b0b = Bsrc[tid + 512];
    float4 b0c = Bsrc[tid + 1024], b0d = Bsrc[tid + 1536];
    float4 b1a = Bsrc[tid + 2048], b1b = Bsrc[tid + 2560];
    float4 b1c = Bsrc[tid + 3072], b1d = Bsrc[tid + 3584];

    // write half 0 + E, start computing while half 1 is still in flight
    Bdst[tid] = b0a; Bdst[tid + 512] = b0b; Bdst[tid + 1024] = b0c; Bdst[tid + 1536] = b0d;
    Es[w * KK + lane] = e0;
    Es[w * KK + 64 + lane] = e1;
    __syncthreads();

    const float2* BsV = (const float2*)Bs;
    float G0 = 0.f, G1 = 0.f, S0 = 0.f, S1 = 0.f;
#pragma unroll 8
    for (int i = 0; i < 64; ++i) {
        float2 bb = BsV[i * CC + lane];
        float2 wg = Es[w * KK + i];
        float t0 = tanh_pre(a2.x + bb.x);
        float t1 = tanh_pre(a2.y + bb.y);
        G0 = fmaf(wg.x, t0, G0);
        G1 = fmaf(wg.y, t1, G1);
        S0 += wg.x;
        S1 += wg.y;
    }

    Bdst[tid + 2048] = b1a; Bdst[tid + 2560] = b1b;
    Bdst[tid + 3072] = b1c; Bdst[tid + 3584] = b1d;
    __syncthreads();

#pragma unroll 8
    for (int i = 64; i < KK; ++i) {
        float2 bb = BsV[i * CC + lane];
        float2 wg = Es[w * KK + i];
        float t0 = tanh_pre(a2.x + bb.x);
        float t1 = tanh_pre(a2.y + bb.y);
        G0 = fmaf(wg.x, t0, G0);
        G1 = fmaf(wg.y, t1, G1);
        S0 += wg.x;
        S1 += wg.y;
    }

    Gsh[w * CC + lane] = make_float2(G0, G1);
    __syncthreads();

    // epilogue matvec per wave (lane = output channel c); G broadcast from LDS
    float acc = 0.f;
#pragma unroll 8
    for (int hh = 0; hh < CC; ++hh) {
        float2 g = Gsh[w * CC + hh];
        acc = fmaf(g.x, W_b2[hh * CC + lane], acc);
        acc = fmaf(g.y, W_b2[CC * CC + hh * CC + lane], acc);
    }
    acc += b_b2[lane] * S0 + b_b2[CC + lane] * S1;

    out[rj * CC + lane] = un + acc * (1.f / 128.f);
}

extern "C" void kernel_launch(void* const* d_in, const int* in_sizes, int n_in,
                              void* d_out, int out_size, void* d_ws, size_t ws_size,
                              hipStream_t stream) {
    const float* t     = (const float*)d_in[0];
    const float* x     = (const float*)d_in[1];
    const float* E     = (const float*)d_in[2];
    const float* W_lin = (const float*)d_in[3];
    const float* b_lin = (const float*)d_in[4];
    const float* W_u1  = (const float*)d_in[5];
    const float* b_u1  = (const float*)d_in[6];
    const float* W_u2  = (const float*)d_in[7];
    const float* b_u2  = (const float*)d_in[8];
    const float* W_b1  = (const float*)d_in[9];
    const float* b_b1  = (const float*)d_in[10];
    const float* W_b2  = (const float*)d_in[11];
    const float* b_b2  = (const float*)d_in[12];
    float* out = (float*)d_out;

    float* ws    = (float*)d_ws;
    float* A2    = ws;                        // 2*N*K*C floats (e-interleaved, prescaled)
    float* B2    = ws + 2 * NB * KK * CC;     // 2*N*K*C
    float* unary = ws + 4 * NB * KK * CC;     // N*K*C

    precompute_kernel<<<NB * KK / 8, 512, 0, stream>>>(
        t, x, W_lin, b_lin, W_u1, b_u1, W_u2, b_u2, W_b1, b_b1, A2, B2, unary);
    binary_kernel<<<NB * KK / 8, 512, 0, stream>>>(
        E, W_b2, b_b2, A2, B2, unary, out);
}

// Round 5
// 25.751 us; speedup vs baseline: 9.2816x; 1.1048x over previous
//
#include <hip/hip_runtime.h>

#define NB 16
#define KK 128
#define CC 64

// 2*log2(e): A2/B2 pre-scaled so tanh(x) = 1 - 2/(exp2(s)+1), s = scaled (a+b)
#define TSCALE 2.8853900817779268f

__device__ __forceinline__ float tanh_pre(float s) {
    // s = 2*log2(e)*x ; tanh(x) = 1 - 2/(2^s + 1)
    return fmaf(-2.f, __builtin_amdgcn_rcpf(__builtin_amdgcn_exp2f(s) + 1.f), 1.f);
}

// SGPR broadcast of lane k's value (k wave-uniform): v_readlane, no LDS traffic
__device__ __forceinline__ float rl(float v, int k) {
    return __builtin_bit_cast(float, __builtin_amdgcn_readlane(__builtin_bit_cast(int, v), k));
}

// Kernel 1: 256 blocks x 512 threads; wave = one row r = n*K+k.
//   h      = [t, x_r] @ W_lin + b_lin
//   unary  = tanh(h@W_u1+b_u1)@W_u2 + b_u2
//   A2[r]  = TSCALE*(h @ W_b1[e][0:C] + b_b1[e])   (receiver/j part, e interleaved)
//   B2[r]  = TSCALE*(h @ W_b1[e][C:2C])            (sender/i part,   e interleaved)
// W_b1 (64 KiB) staged in LDS once per block; broadcasts via readlane (VALU, not LDS).
__global__ __launch_bounds__(512) void precompute_kernel(
    const float* __restrict__ t, const float* __restrict__ x,
    const float* __restrict__ W_lin, const float* __restrict__ b_lin,
    const float* __restrict__ W_u1, const float* __restrict__ b_u1,
    const float* __restrict__ W_u2, const float* __restrict__ b_u2,
    const float* __restrict__ W_b1, const float* __restrict__ b_b1,
    float* __restrict__ A2, float* __restrict__ B2, float* __restrict__ unary)
{
    __shared__ float Wb1s[2 * 2 * CC * CC];   // 64 KiB, same layout as W_b1 [ET][2C][C]

    const int tid = threadIdx.x;
    {   // stage W_b1: 16384 floats = 4096 float4, 8 per thread
        const float4* src = (const float4*)W_b1;
        float4* dst = (float4*)Wb1s;
#pragma unroll
        for (int it = 0; it < 8; ++it) dst[tid + it * 512] = src[tid + it * 512];
    }
    __syncthreads();

    const int lane = tid & 63;
    const int r    = blockIdx.x * 8 + (tid >> 6);   // row in [0, N*K)

    const float xv = x[r * CC + lane];
    float h = fmaf(t[0], W_lin[lane], b_lin[lane]);
#pragma unroll
    for (int k = 0; k < CC; ++k) {
        h = fmaf(rl(xv, k), W_lin[(k + 1) * CC + lane], h);
    }

    float u1 = b_u1[lane];
    float a0 = b_b1[lane], a1 = b_b1[CC + lane];
    float bb0 = 0.f, bb1 = 0.f;
#pragma unroll 4
    for (int k = 0; k < CC; ++k) {
        float hk = rl(h, k);
        u1  = fmaf(hk, W_u1[k * CC + lane], u1);
        a0  = fmaf(hk, Wb1s[k * CC + lane], a0);
        bb0 = fmaf(hk, Wb1s[(CC + k) * CC + lane], bb0);
        a1  = fmaf(hk, Wb1s[2 * CC * CC + k * CC + lane], a1);
        bb1 = fmaf(hk, Wb1s[2 * CC * CC + (CC + k) * CC + lane], bb1);
    }

    float tu = tanh_pre(TSCALE * u1);
    float u2 = b_u2[lane];
#pragma unroll
    for (int k = 0; k < CC; ++k) {
        u2 = fmaf(rl(tu, k), W_u2[k * CC + lane], u2);
    }

    const int idx = r * CC + lane;
    unary[idx] = u2;
    ((float2*)A2)[idx] = make_float2(TSCALE * a0, TSCALE * a1);
    ((float2*)B2)[idx] = make_float2(TSCALE * bb0, TSCALE * bb1);
}

// Kernel 2: 256 blocks x 1024 threads (16 waves, 4/SIMD); block = (n, 8 j).
// Wave = (j-pair p, i-quarter q): 2 j share each bb LDS read; 32 i each.
//   G[e,h] = sum_i E[n,i,j,e] * tanh_pre(A[e,n,j,h] + B[e,n,i,h])
//   out[n,j,c] = unary + (1/K) * sum_e (G[e]@W_b2[e] + b_b2[e]*sum_i E)
__global__ __launch_bounds__(1024, 4) void binary_kernel(
    const float* __restrict__ E, const float* __restrict__ W_b2,
    const float* __restrict__ b_b2, const float* __restrict__ A2,
    const float* __restrict__ B2, const float* __restrict__ unary,
    float* __restrict__ out)
{
    __shared__ float  Bs[KK * CC * 2];   // 64 KiB  [i][h][e] (linear copy of B2[n])
    __shared__ float4 Es4[4][KK];        //  8 KiB  [jpair][i] = (jA e0, jA e1, jB e0, jB e1)
    __shared__ float4 Gsh4[16][CC];      // 16 KiB  per-wave G partials

    const int tid  = threadIdx.x;
    const int lane = tid & 63;
    const int w    = tid >> 6;           // 0..15
    const int n    = blockIdx.x >> 4;
    const int j0   = (blockIdx.x & 15) * 8;

    // ---- stage B2[n] (64 KiB, linear) and E columns ----
    const float4* Bsrc = (const float4*)(B2 + n * KK * CC * 2);
    float4 s0 = Bsrc[tid], s1 = Bsrc[tid + 1024], s2 = Bsrc[tid + 2048], s3 = Bsrc[tid + 3072];
    const int jl = tid & 7, ii = tid >> 3;
    float2 ev = ((const float2*)E)[(n * KK + ii) * KK + j0 + jl];

    float4* Bdst = (float4*)Bs;
    Bdst[tid] = s0; Bdst[tid + 1024] = s1; Bdst[tid + 2048] = s2; Bdst[tid + 3072] = s3;
    ((float2*)Es4)[((jl >> 1) * KK + ii) * 2 + (jl & 1)] = ev;
    __syncthreads();

    // ---- main loop ----
    const int p  = w & 3;                // j-pair
    const int q  = w >> 2;               // i-quarter
    const int jA = j0 + 2 * p;
    const float2 aA = ((const float2*)A2)[(n * KK + jA) * CC + lane];
    const float2 aB = ((const float2*)A2)[(n * KK + jA + 1) * CC + lane];

    const float2* BsV = (const float2*)Bs;
    float GA0 = 0.f, GA1 = 0.f, GB0 = 0.f, GB1 = 0.f;
#pragma unroll 8
    for (int i = q * 32; i < q * 32 + 32; ++i) {
        float2 bb = BsV[i * CC + lane];  // shared by both j of the pair
        float4 wg = Es4[p][i];           // uniform broadcast read
        float tA0 = tanh_pre(aA.x + bb.x);
        float tA1 = tanh_pre(aA.y + bb.y);
        float tB0 = tanh_pre(aB.x + bb.x);
        float tB1 = tanh_pre(aB.y + bb.y);
        GA0 = fmaf(wg.x, tA0, GA0);  GA1 = fmaf(wg.y, tA1, GA1);
        GB0 = fmaf(wg.z, tB0, GB0);  GB1 = fmaf(wg.w, tB1, GB1);
    }
    Gsh4[w][lane] = make_float4(GA0, GA1, GB0, GB1);
    __syncthreads();

    // ---- reduce the 4 i-quarters (waves 0..3, one per j-pair) ----
    if (w < 4) {
        float4 g0 = Gsh4[w][lane],     g1 = Gsh4[4 + w][lane];
        float4 g2 = Gsh4[8 + w][lane], g3 = Gsh4[12 + w][lane];
        Gsh4[w][lane] = make_float4(g0.x + g1.x + g2.x + g3.x, g0.y + g1.y + g2.y + g3.y,
                                    g0.z + g1.z + g2.z + g3.z, g0.w + g1.w + g2.w + g3.w);
    }
    __syncthreads();

    // ---- epilogue: waves 0..7, wave = one j; lane = output channel c ----
    if (w < 8) {
        const int pj = w >> 1;
        const int rj = n * KK + j0 + w;
        // float2 view selecting this j's half of the pair's float4
        const float2* Gp = ((const float2*)Gsh4) + pj * CC * 2 + (w & 1);
        float acc = 0.f;
#pragma unroll 8
        for (int h = 0; h < CC; ++h) {
            float2 g = Gp[h * 2];        // uniform broadcast read
            acc = fmaf(g.x, W_b2[h * CC + lane], acc);
            acc = fmaf(g.y, W_b2[CC * CC + h * CC + lane], acc);
        }
        // S[e] = sum_i E[n,i,j,e]
        const float2* Ep2 = ((const float2*)Es4) + pj * KK * 2 + (w & 1);
        float2 eA = Ep2[lane * 2], eB = Ep2[(64 + lane) * 2];
        float S0 = eA.x + eB.x, S1 = eA.y + eB.y;
#pragma unroll
        for (int m = 32; m; m >>= 1) { S0 += __shfl_xor(S0, m); S1 += __shfl_xor(S1, m); }
        acc += b_b2[lane] * S0 + b_b2[CC + lane] * S1;
        out[rj * CC + lane] = unary[rj * CC + lane] + acc * (1.f / 128.f);
    }
}

extern "C" void kernel_launch(void* const* d_in, const int* in_sizes, int n_in,
                              void* d_out, int out_size, void* d_ws, size_t ws_size,
                              hipStream_t stream) {
    const float* t     = (const float*)d_in[0];
    const float* x     = (const float*)d_in[1];
    const float* E     = (const float*)d_in[2];
    const float* W_lin = (const float*)d_in[3];
    const float* b_lin = (const float*)d_in[4];
    const float* W_u1  = (const float*)d_in[5];
    const float* b_u1  = (const float*)d_in[6];
    const float* W_u2  = (const float*)d_in[7];
    const float* b_u2  = (const float*)d_in[8];
    const float* W_b1  = (const float*)d_in[9];
    const float* b_b1  = (const float*)d_in[10];
    const float* W_b2  = (const float*)d_in[11];
    const float* b_b2  = (const float*)d_in[12];
    float* out = (float*)d_out;

    float* ws    = (float*)d_ws;
    float* A2    = ws;                        // 2*N*K*C floats (e-interleaved, prescaled)
    float* B2    = ws + 2 * NB * KK * CC;     // 2*N*K*C
    float* unary = ws + 4 * NB * KK * CC;     // N*K*C

    precompute_kernel<<<NB * KK / 8, 512, 0, stream>>>(
        t, x, W_lin, b_lin, W_u1, b_u1, W_u2, b_u2, W_b1, b_b1, A2, B2, unary);
    binary_kernel<<<NB * 16, 1024, 0, stream>>>(
        E, W_b2, b_b2, A2, B2, unary, out);
}

// Round 6
// 25.585 us; speedup vs baseline: 9.3419x; 1.0065x over previous
//
#include <hip/hip_runtime.h>

#define NB 16
#define KK 128
#define CC 64

// 2*log2(e): A2/B2 pre-scaled so tanh(x) = 1 - 2/(exp2(s)+1), s = scaled (a+b)
#define TSCALE 2.8853900817779268f

__device__ __forceinline__ float tanh_pre(float s) {
    return fmaf(-2.f, __builtin_amdgcn_rcpf(__builtin_amdgcn_exp2f(s) + 1.f), 1.f);
}

// SGPR broadcast of lane k's value (k wave-uniform): v_readlane, no LDS traffic
__device__ __forceinline__ float rl(float v, int k) {
    return __builtin_bit_cast(float, __builtin_amdgcn_readlane(__builtin_bit_cast(int, v), k));
}

// Kernel 1: 256 blocks x 512 threads; wave = one row r = n*K+k.
// ALL big weights (W_b1 64K, W_u1 16K, W_u2 16K) staged in LDS (96 KiB);
// only W_lin (16.6 KB) streams from global -> fits L1 alone, no thrash.
__global__ __launch_bounds__(512) void precompute_kernel(
    const float* __restrict__ t, const float* __restrict__ x,
    const float* __restrict__ W_lin, const float* __restrict__ b_lin,
    const float* __restrict__ W_u1, const float* __restrict__ b_u1,
    const float* __restrict__ W_u2, const float* __restrict__ b_u2,
    const float* __restrict__ W_b1, const float* __restrict__ b_b1,
    float* __restrict__ A2, float* __restrict__ B2, float* __restrict__ unary)
{
    __shared__ float Ws[24576];   // 96 KiB: W_b1 [0,16384) | W_u1 [16384,20480) | W_u2 [20480,24576)

    const int tid = threadIdx.x;
    {
        const float4* s1 = (const float4*)W_b1;   // 4096 float4
        const float4* s2 = (const float4*)W_u1;   // 1024
        const float4* s3 = (const float4*)W_u2;   // 1024
        float4* dst = (float4*)Ws;
#pragma unroll
        for (int it = 0; it < 8; ++it) dst[tid + it * 512] = s1[tid + it * 512];
        dst[4096 + tid] = s2[tid];
        dst[4096 + 512 + tid] = s2[512 + tid];
        dst[5120 + tid] = s3[tid];
        dst[5120 + 512 + tid] = s3[512 + tid];
    }
    __syncthreads();

    const int lane = tid & 63;
    const int r    = blockIdx.x * 8 + (tid >> 6);   // row in [0, N*K)

    const float xv = x[r * CC + lane];
    float h = fmaf(t[0], W_lin[lane], b_lin[lane]);
#pragma unroll
    for (int k = 0; k < CC; ++k) {
        h = fmaf(rl(xv, k), W_lin[(k + 1) * CC + lane], h);
    }

    float u1 = b_u1[lane];
    float a0 = b_b1[lane], a1 = b_b1[CC + lane];
    float bb0 = 0.f, bb1 = 0.f;
#pragma unroll 4
    for (int k = 0; k < CC; ++k) {
        float hk = rl(h, k);
        u1  = fmaf(hk, Ws[16384 + k * CC + lane], u1);
        a0  = fmaf(hk, Ws[k * CC + lane], a0);
        bb0 = fmaf(hk, Ws[(CC + k) * CC + lane], bb0);
        a1  = fmaf(hk, Ws[2 * CC * CC + k * CC + lane], a1);
        bb1 = fmaf(hk, Ws[2 * CC * CC + (CC + k) * CC + lane], bb1);
    }

    float tu = tanh_pre(TSCALE * u1);
    float u2 = b_u2[lane];
#pragma unroll
    for (int k = 0; k < CC; ++k) {
        u2 = fmaf(rl(tu, k), Ws[20480 + k * CC + lane], u2);
    }

    const int idx = r * CC + lane;
    unary[idx] = u2;
    ((float2*)A2)[idx] = make_float2(TSCALE * a0, TSCALE * a1);
    ((float2*)B2)[idx] = make_float2(TSCALE * bb0, TSCALE * bb1);
}

// Kernel 2: 256 blocks x 1024 threads (16 waves, 4/SIMD); block = (n, 8 j).
// Wave = (j-pair p, i-quarter q). Paired-rcp tanh: one v_rcp serves both j of
// the pair (trans/iter 8->6).
__global__ __launch_bounds__(1024, 4) void binary_kernel(
    const float* __restrict__ E, const float* __restrict__ W_b2,
    const float* __restrict__ b_b2, const float* __restrict__ A2,
    const float* __restrict__ B2, const float* __restrict__ unary,
    float* __restrict__ out)
{
    __shared__ float  Bs[KK * CC * 2];   // 64 KiB  [i][h][e] (linear copy of B2[n])
    __shared__ float4 Es4[4][KK];        //  8 KiB  [jpair][i] = (jA e0, jA e1, jB e0, jB e1)
    __shared__ float4 Gsh4[16][CC];      // 16 KiB  per-wave G partials

    const int tid  = threadIdx.x;
    const int lane = tid & 63;
    const int w    = tid >> 6;           // 0..15
    const int n    = blockIdx.x >> 4;
    const int j0   = (blockIdx.x & 15) * 8;

    // ---- stage B2[n] (64 KiB, linear) and E columns ----
    const float4* Bsrc = (const float4*)(B2 + n * KK * CC * 2);
    float4 s0 = Bsrc[tid], s1 = Bsrc[tid + 1024], s2 = Bsrc[tid + 2048], s3 = Bsrc[tid + 3072];
    const int jl = tid & 7, ii = tid >> 3;
    float2 ev = ((const float2*)E)[(n * KK + ii) * KK + j0 + jl];

    float4* Bdst = (float4*)Bs;
    Bdst[tid] = s0; Bdst[tid + 1024] = s1; Bdst[tid + 2048] = s2; Bdst[tid + 3072] = s3;
    ((float2*)Es4)[((jl >> 1) * KK + ii) * 2 + (jl & 1)] = ev;
    __syncthreads();

    // ---- main loop ----
    const int p  = w & 3;                // j-pair
    const int q  = w >> 2;               // i-quarter
    const int jA = j0 + 2 * p;
    const float2 aA = ((const float2*)A2)[(n * KK + jA) * CC + lane];
    const float2 aB = ((const float2*)A2)[(n * KK + jA + 1) * CC + lane];

    const float2* BsV = (const float2*)Bs;
    float GA0 = 0.f, GA1 = 0.f, GB0 = 0.f, GB1 = 0.f;
#pragma unroll 8
    for (int i = q * 32; i < q * 32 + 32; ++i) {
        float2 bb = BsV[i * CC + lane];  // shared by both j of the pair
        float4 wg = Es4[p][i];           // uniform broadcast read
        float dA0 = __builtin_amdgcn_exp2f(aA.x + bb.x) + 1.f;
        float dB0 = __builtin_amdgcn_exp2f(aB.x + bb.x) + 1.f;
        float dA1 = __builtin_amdgcn_exp2f(aA.y + bb.y) + 1.f;
        float dB1 = __builtin_amdgcn_exp2f(aB.y + bb.y) + 1.f;
        float m0 = -2.f * __builtin_amdgcn_rcpf(dA0 * dB0);
        float m1 = -2.f * __builtin_amdgcn_rcpf(dA1 * dB1);
        float tA0 = fmaf(dB0, m0, 1.f);   // 1 - 2/dA0
        float tB0 = fmaf(dA0, m0, 1.f);   // 1 - 2/dB0
        float tA1 = fmaf(dB1, m1, 1.f);
        float tB1 = fmaf(dA1, m1, 1.f);
        GA0 = fmaf(wg.x, tA0, GA0);  GA1 = fmaf(wg.y, tA1, GA1);
        GB0 = fmaf(wg.z, tB0, GB0);  GB1 = fmaf(wg.w, tB1, GB1);
    }
    Gsh4[w][lane] = make_float4(GA0, GA1, GB0, GB1);
    __syncthreads();

    // ---- reduce the 4 i-quarters (waves 0..3, one per j-pair) ----
    if (w < 4) {
        float4 g0 = Gsh4[w][lane],     g1 = Gsh4[4 + w][lane];
        float4 g2 = Gsh4[8 + w][lane], g3 = Gsh4[12 + w][lane];
        Gsh4[w][lane] = make_float4(g0.x + g1.x + g2.x + g3.x, g0.y + g1.y + g2.y + g3.y,
                                    g0.z + g1.z + g2.z + g3.z, g0.w + g1.w + g2.w + g3.w);
    }
    __syncthreads();

    // ---- epilogue: waves 0..7, wave = one j; lane = output channel c ----
    if (w < 8) {
        const int pj = w >> 1;
        const int rj = n * KK + j0 + w;
        const float2* Gp = ((const float2*)Gsh4) + pj * CC * 2 + (w & 1);
        float acc = 0.f;
#pragma unroll 8
        for (int h = 0; h < CC; ++h) {
            float2 g = Gp[h * 2];        // uniform broadcast read
            acc = fmaf(g.x, W_b2[h * CC + lane], acc);
            acc = fmaf(g.y, W_b2[CC * CC + h * CC + lane], acc);
        }
        const float2* Ep2 = ((const float2*)Es4) + pj * KK * 2 + (w & 1);
        float2 eA = Ep2[lane * 2], eB = Ep2[(64 + lane) * 2];
        float S0 = eA.x + eB.x, S1 = eA.y + eB.y;
#pragma unroll
        for (int m = 32; m; m >>= 1) { S0 += __shfl_xor(S0, m); S1 += __shfl_xor(S1, m); }
        acc += b_b2[lane] * S0 + b_b2[CC + lane] * S1;
        out[rj * CC + lane] = unary[rj * CC + lane] + acc * (1.f / 128.f);
    }
}

extern "C" void kernel_launch(void* const* d_in, const int* in_sizes, int n_in,
                              void* d_out, int out_size, void* d_ws, size_t ws_size,
                              hipStream_t stream) {
    const float* t     = (const float*)d_in[0];
    const float* x     = (const float*)d_in[1];
    const float* E     = (const float*)d_in[2];
    const float* W_lin = (const float*)d_in[3];
    const float* b_lin = (const float*)d_in[4];
    const float* W_u1  = (const float*)d_in[5];
    const float* b_u1  = (const float*)d_in[6];
    const float* W_u2  = (const float*)d_in[7];
    const float* b_u2  = (const float*)d_in[8];
    const float* W_b1  = (const float*)d_in[9];
    const float* b_b1  = (const float*)d_in[10];
    const float* W_b2  = (const float*)d_in[11];
    const float* b_b2  = (const float*)d_in[12];
    float* out = (float*)d_out;

    float* ws    = (float*)d_ws;
    float* A2    = ws;                        // 2*N*K*C floats (e-interleaved, prescaled)
    float* B2    = ws + 2 * NB * KK * CC;     // 2*N*K*C
    float* unary = ws + 4 * NB * KK * CC;     // N*K*C

    precompute_kernel<<<NB * KK / 8, 512, 0, stream>>>(
        t, x, W_lin, b_lin, W_u1, b_u1, W_u2, b_u2, W_b1, b_b1, A2, B2, unary);
    binary_kernel<<<NB * 16, 1024, 0, stream>>>(
        E, W_b2, b_b2, A2, B2, unary, out);
}